// Round 2
// baseline (323.384 us; speedup 1.0000x reference)
//
#include <hip/hip_runtime.h>
#include <hip/hip_fp16.h>

#define QN 900
#define CN 91
#define TOTN (QN * CN)   // 81900
#define KSEL 300
#define BN 4
#define OUTW 448
#define MASKPIX (OUTW * OUTW)        // 200704
#define OFFS_LABELS (BN * KSEL)      // 1200
#define OFFS_BOXES  (2 * BN * KSEL)  // 2400
#define OFFS_MASKS  (6 * BN * KSEL)  // 7200
#define MAXC 1024
#define BT 1024

// monotonic key: larger float -> larger unsigned
static __device__ __forceinline__ unsigned fkey(float f) {
    unsigned u = __float_as_uint(f);
    return (u & 0x80000000u) ? ~u : (u | 0x80000000u);
}

__global__ __launch_bounds__(BT) void select_kernel(
    const float* __restrict__ logits, const float* __restrict__ boxes,
    const int* __restrict__ tsz, float* out, int* qsel)
{
    const int b = blockIdx.x;
    const int tid = threadIdx.x;
    const float* lg = logits + (size_t)b * TOTN;

    __shared__ unsigned hist[256];
    __shared__ int sh_bin, sh_want;
    __shared__ unsigned sh_cnt;
    __shared__ int cidx[MAXC];
    __shared__ unsigned ckey[MAXC];

    // ---- radix select: T = key of the 300th-largest element ----
    unsigned prefix = 0;
    int want = KSEL;
    for (int round = 0; round < 4; ++round) {
        const int shift = 24 - 8 * round;
        const unsigned pmask = (round == 0) ? 0u : (0xFFFFFFFFu << (shift + 8));
        if (tid < 256) hist[tid] = 0;
        __syncthreads();
        for (int i = tid; i < TOTN; i += BT) {
            unsigned key = fkey(lg[i]);
            if ((key & pmask) == prefix)
                atomicAdd(&hist[(key >> shift) & 255u], 1u);
        }
        __syncthreads();
        if (tid == 0) {
            int acc = 0;
            int bin = 255;
            for (; bin > 0; --bin) {
                int c = (int)hist[bin];
                if (acc + c >= want) break;
                acc += c;
            }
            sh_bin = bin;
            sh_want = want - acc;
        }
        __syncthreads();
        prefix |= ((unsigned)sh_bin << shift);
        want = sh_want;
        __syncthreads();
    }
    const unsigned T = prefix;

    // ---- gather candidates: key >= T (count is 300 + rare exact dups) ----
    if (tid == 0) sh_cnt = 0;
    __syncthreads();
    for (int i = tid; i < TOTN; i += BT) {
        unsigned key = fkey(lg[i]);
        if (key >= T) {
            unsigned pos = atomicAdd(&sh_cnt, 1u);
            if (pos < MAXC) { cidx[pos] = i; ckey[pos] = key; }
        }
    }
    __syncthreads();
    const int ncand = min((int)sh_cnt, MAXC);

    const float fh = (float)tsz[b * 2 + 0];
    const float fw = (float)tsz[b * 2 + 1];

    // ---- exact rank (desc by key, asc by index) -> direct scatter ----
    for (int c = tid; c < ncand; c += BT) {
        const unsigned kc = ckey[c];
        const int ic = cidx[c];
        int rank = 0;
        for (int s = 0; s < ncand; ++s) {
            unsigned ks = ckey[s];
            if (ks > kc || (ks == kc && cidx[s] < ic)) ++rank;
        }
        if (rank < KSEL) {
            float lf = lg[ic];
            float score = 1.0f / (1.0f + expf(-lf));
            int q = ic / CN;
            int label = ic - q * CN;

            out[b * KSEL + rank] = score;
            out[OFFS_LABELS + b * KSEL + rank] = (float)label;

            const float* bx = boxes + ((size_t)b * QN + q) * 4;
            float cx = bx[0], cy = bx[1], ww = bx[2], hh = bx[3];
            float* ob = out + OFFS_BOXES + ((size_t)(b * KSEL + rank)) * 4;
            ob[0] = (cx - 0.5f * ww) * fw;
            ob[1] = (cy - 0.5f * hh) * fh;
            ob[2] = (cx + 0.5f * ww) * fw;
            ob[3] = (cy + 0.5f * hh) * fh;

            qsel[b * KSEL + rank] = q;
        }
    }
}

#define SPLIT 4   // blocks per mask; each does 112 rows (7 groups of 16)
#define RG 16

__global__ __launch_bounds__(256) void mask_kernel(
    const float* __restrict__ masks, const int* __restrict__ qsel, float* out)
{
    const int mk = blockIdx.x / SPLIT;     // 0..BN*KSEL-1
    const int part = blockIdx.x % SPLIT;
    const int b = mk / KSEL;
    const int q = qsel[mk];
    const float* src = masks + ((size_t)b * QN + q) * 784;

    __shared__ float sm[784];
    __shared__ float vrow[RG][29];

    for (int i = threadIdx.x; i < 784; i += 256)
        sm[i] = __half2float(__float2half(src[i]));  // ref casts to fp16 before resize
    __syncthreads();

    float* obase = out + OFFS_MASKS + (size_t)mk * MASKPIX;

    for (int rg = part * 7; rg < part * 7 + 7; ++rg) {
        // vertical lerp into row cache
        for (int t = threadIdx.x; t < RG * 28; t += 256) {
            int rr = t / 28, c2 = t % 28;
            int y = rg * RG + rr;
            float sy = y * 0.0625f - 0.46875f;
            float yf = floorf(sy);
            float ty = sy - yf;
            int iy = (int)yf;
            int y0 = iy < 0 ? 0 : iy;
            int y1 = (iy + 1 > 27) ? 27 : iy + 1;
            float a = sm[y0 * 28 + c2];
            float bb = sm[y1 * 28 + c2];
            vrow[rr][c2] = a + ty * (bb - a);
        }
        __syncthreads();
        // horizontal lerp, 4 f32 per 16B store
        for (int t = threadIdx.x; t < RG * 112; t += 256) {
            int rr = t / 112, g = t % 112;
            int xb = g * 4;
            float px[4];
#pragma unroll
            for (int j = 0; j < 4; ++j) {
                int x = xb + j;
                float sx = x * 0.0625f - 0.46875f;
                float xf = floorf(sx);
                float tx = sx - xf;
                int ix = (int)xf;
                int x0 = ix < 0 ? 0 : ix;
                int x1 = (ix + 1 > 27) ? 27 : ix + 1;
                float a = vrow[rr][x0];
                float bb = vrow[rr][x1];
                float v = a + tx * (bb - a);
                px[j] = __half2float(__float2half(v));  // ref output dtype is f16
            }
            float4 w;
            w.x = px[0]; w.y = px[1]; w.z = px[2]; w.w = px[3];
            int y = rg * RG + rr;
            *reinterpret_cast<float4*>(obase + (size_t)y * OUTW + xb) = w;
        }
        __syncthreads();
    }
}

extern "C" void kernel_launch(void* const* d_in, const int* in_sizes, int n_in,
                              void* d_out, int out_size, void* d_ws, size_t ws_size,
                              hipStream_t stream) {
    const float* pred_logits = (const float*)d_in[0];
    const float* pred_boxes  = (const float*)d_in[1];
    const float* pred_masks  = (const float*)d_in[2];
    const int*   target_sz   = (const int*)d_in[3];
    float* out = (float*)d_out;
    int* qsel = (int*)d_ws;

    select_kernel<<<BN, BT, 0, stream>>>(pred_logits, pred_boxes, target_sz, out, qsel);
    mask_kernel<<<BN * KSEL * SPLIT, 256, 0, stream>>>(pred_masks, qsel, out);
}